// Round 1
// baseline (1871.555 us; speedup 1.0000x reference)
//
#include <hip/hip_runtime.h>
#include <math.h>

// Shapes: B=2, T=2048, D=1024, H=8, S=32, Dh=128, 3D=3072, B*T=4096
// ws layout (floats):
//   qT[2][8][2048][128]   @ 0         (4,194,304)   q in [b][h][t][dh]
//   kT                    @ 4194304
//   vT                    @ 8388608
//   qa[2][8][2048][32]    @ 12582912  (1,048,576)   q_weights*amplitude
//   kw[2][8][2048][32]    @ 13631488
//   mrow[2][8][2048]      @ 14680064  (32,768)      softmax row max
//   lrow[2][8][2048]      @ 14712832  (32,768)      softmax row sum
//   aout[4096][1024]      @ 14745600  (4,194,304)   attention@V, (B*T, D)
// total 18,939,904 floats = 75.8 MB  (ws_size assumed >= this)

// ---------------------------------------------------------------------------
// GEMM fp32: C = A(4096xK=1024) @ W(KxN) + bias.  128x128 tile, BK=16,
// 256 threads, 8x8 micro-tile (split 4+4 at stride 64 to keep LDS reads 2-way).
// SCATTER=true: N=3072, scatter into qT/kT/vT  [b][h][t][dh].
// ---------------------------------------------------------------------------
template <int N, bool SCATTER>
__global__ __launch_bounds__(256) void gemm_f32(
    const float* __restrict__ A, const float* __restrict__ W,
    const float* __restrict__ bias,
    float* __restrict__ out0, float* __restrict__ out1, float* __restrict__ out2) {
  __shared__ __align__(16) float As[16][128];
  __shared__ __align__(16) float Bs[16][128];
  const int t = threadIdx.x;
  const int col0 = blockIdx.x * 128;
  const int row0 = blockIdx.y * 128;
  const int tm = t & 15, tn = t >> 4;
  const int K = 1024;
  float acc[8][8];
#pragma unroll
  for (int i = 0; i < 8; i++)
#pragma unroll
    for (int j = 0; j < 8; j++) acc[i][j] = 0.f;

  const int am = t & 127, ak = (t >> 7) * 8;      // A tile: 128 rows x 16 k
  const int bk = t >> 4, bn = (t & 15) * 8;       // B tile: 16 k x 128 cols

  for (int k0 = 0; k0 < K; k0 += 16) {
    float4 a0 = *(const float4*)(A + (row0 + am) * K + k0 + ak);
    float4 a1 = *(const float4*)(A + (row0 + am) * K + k0 + ak + 4);
    float4 b0 = *(const float4*)(W + (k0 + bk) * N + col0 + bn);
    float4 b1 = *(const float4*)(W + (k0 + bk) * N + col0 + bn + 4);
    __syncthreads();
    As[ak + 0][am] = a0.x; As[ak + 1][am] = a0.y;
    As[ak + 2][am] = a0.z; As[ak + 3][am] = a0.w;
    As[ak + 4][am] = a1.x; As[ak + 5][am] = a1.y;
    As[ak + 6][am] = a1.z; As[ak + 7][am] = a1.w;
    *(float4*)&Bs[bk][bn] = b0;
    *(float4*)&Bs[bk][bn + 4] = b1;
    __syncthreads();
#pragma unroll
    for (int kk = 0; kk < 16; kk++) {
      float4 av0 = *(const float4*)&As[kk][tm * 4];
      float4 av1 = *(const float4*)&As[kk][64 + tm * 4];
      float4 bv0 = *(const float4*)&Bs[kk][tn * 4];
      float4 bv1 = *(const float4*)&Bs[kk][64 + tn * 4];
      float a_[8] = {av0.x, av0.y, av0.z, av0.w, av1.x, av1.y, av1.z, av1.w};
      float b_[8] = {bv0.x, bv0.y, bv0.z, bv0.w, bv1.x, bv1.y, bv1.z, bv1.w};
#pragma unroll
      for (int i = 0; i < 8; i++)
#pragma unroll
        for (int j = 0; j < 8; j++) acc[i][j] += a_[i] * b_[j];
    }
  }
#pragma unroll
  for (int hi = 0; hi < 2; hi++) {
#pragma unroll
    for (int ii = 0; ii < 4; ii++) {
      int row = row0 + hi * 64 + tm * 4 + ii;
#pragma unroll
      for (int hj = 0; hj < 2; hj++) {
#pragma unroll
        for (int jj = 0; jj < 4; jj++) {
          int col = col0 + hj * 64 + tn * 4 + jj;
          float v = acc[hi * 4 + ii][hj * 4 + jj] + bias[col];
          if (SCATTER) {
            int three = col >> 10;          // uniform per (block,hj) run
            int h = (col >> 7) & 7;
            int dh = col & 127;
            int bb = row >> 11, tt = row & 2047;
            float* dst = (three == 0) ? out0 : ((three == 1) ? out1 : out2);
            dst[((bb * 8 + h) * 2048 + tt) * 128 + dh] = v;
          } else {
            out0[row * N + col] = v;
          }
        }
      }
    }
  }
}

// ---------------------------------------------------------------------------
// Splat weights: per (b,t,which in {q,k}): for all (h,s):
//   d2 = max(|q|^2 + |c|^2 - 2 q.c, 0);  w = exp(-0.5*d2/(exp(ls)+eps)^2)
//   qa = w*exp(la) (q only); kw = w.   Output layout [b][h][t][s].
// ---------------------------------------------------------------------------
__global__ __launch_bounds__(256) void splat_weights(
    const float* __restrict__ qT, const float* __restrict__ kT,
    const float* __restrict__ ctr, const float* __restrict__ ls,
    const float* __restrict__ la, float* __restrict__ qa, float* __restrict__ kw) {
  const int bt = blockIdx.x;             // b*2048 + t
  const int which = blockIdx.y;          // 0=q, 1=k
  const int b = bt >> 11, tt = bt & 2047;
  const float* src = which ? kT : qT;
  __shared__ __align__(16) float rowbuf[1024];
  {
    int flat = threadIdx.x * 4;
    int hh = flat >> 7, d = flat & 127;
    *(float4*)&rowbuf[flat] = *(const float4*)(src + ((b * 8 + hh) * 2048 + tt) * 128 + d);
  }
  __syncthreads();
  const int h = threadIdx.x >> 5, s = threadIdx.x & 31;
  const float* c = ctr + (h * 32 + s) * 128;
  const float* qr = &rowbuf[h * 128];
  float qsq = 0.f, csq = 0.f, dot = 0.f;
#pragma unroll
  for (int u = 0; u < 32; u++) {
    float4 cv = *(const float4*)(c + u * 4);
    float4 qv = *(const float4*)(qr + u * 4);
    qsq += qv.x * qv.x + qv.y * qv.y + qv.z * qv.z + qv.w * qv.w;
    csq += cv.x * cv.x + cv.y * cv.y + cv.z * cv.z + cv.w * cv.w;
    dot += qv.x * cv.x + qv.y * cv.y + qv.z * cv.z + qv.w * cv.w;
  }
  float d2 = fmaxf(qsq + csq - 2.f * dot, 0.f);
  float scale = __expf(ls[h * 32 + s]);
  float inv = 1.0f / (scale + 1e-6f);
  float w = __expf(-0.5f * d2 * inv * inv);
  if (which == 0) w *= __expf(la[h * 32 + s]);
  float* dst = which ? kw : qa;
  dst[((b * 8 + h) * 2048 + tt) * 32 + s] = w;
}

// ---------------------------------------------------------------------------
// Attention m/l + PV.  One block = (b, h, 32 i-rows).  Pass B: online softmax
// (m,l) over all 2048 j.  Pass C: recompute p into LDS, PV-accumulate.
// Writes mrow/lrow (for attn_write) and aout (B*T, D) = attention @ V.
// ---------------------------------------------------------------------------
__global__ __launch_bounds__(256) void attn_mlpv(
    const float* __restrict__ qa, const float* __restrict__ kw,
    const float* __restrict__ vT, const float* __restrict__ temp,
    float* __restrict__ mrow, float* __restrict__ lrow, float* __restrict__ aout) {
  __shared__ __align__(16) float kws[32][32];    // 4 KB
  __shared__ __align__(16) float vs[32][128];    // 16 KB
  __shared__ float ps[32][33];                   // 4.2 KB
  __shared__ float redm[16][32];
  __shared__ float redl[16][32];                 // 4 KB
  const int t = threadIdx.x;
  const int bx = blockIdx.x;
  const int it = bx & 63, h = (bx >> 6) & 7, b = bx >> 9;
  const int i0 = it * 32;
  const int bh = b * 8 + h;
  const float invT = 1.0f / temp[0];
  const float* qabase = qa + (bh * 2048 + i0) * 32;
  const float* kwbase = kw + bh * 2048 * 32;
  const float* vbase = vT + bh * 2048 * 128;

  const int i2 = t & 15;       // this thread's rows: i2 and i2+16
  const int jslot = t >> 4;    // 0..15
  float4 qva[8], qvb[8];
#pragma unroll
  for (int u = 0; u < 8; u++) {
    qva[u] = *(const float4*)(qabase + i2 * 32 + u * 4);
    qvb[u] = *(const float4*)(qabase + (i2 + 16) * 32 + u * 4);
  }
  float m1 = -1e30f, l1 = 0.f, m2 = -1e30f, l2 = 0.f;
  for (int jc = 0; jc < 2048; jc += 32) {
    __syncthreads();
    *(float4*)((float*)kws + t * 4) = *(const float4*)(kwbase + jc * 32 + t * 4);
    __syncthreads();
#pragma unroll
    for (int u = 0; u < 2; u++) {
      int jl = jslot * 2 + u;
      float da = 0.f, db = 0.f;
#pragma unroll
      for (int sq = 0; sq < 8; sq++) {
        float4 kv = *(const float4*)&kws[jl][sq * 4];
        da += qva[sq].x * kv.x + qva[sq].y * kv.y + qva[sq].z * kv.z + qva[sq].w * kv.w;
        db += qvb[sq].x * kv.x + qvb[sq].y * kv.y + qvb[sq].z * kv.z + qvb[sq].w * kv.w;
      }
      float la_ = da * invT, lb_ = db * invT;
      float nm = fmaxf(m1, la_);
      l1 = l1 * __expf(m1 - nm) + __expf(la_ - nm); m1 = nm;
      nm = fmaxf(m2, lb_);
      l2 = l2 * __expf(m2 - nm) + __expf(lb_ - nm); m2 = nm;
    }
  }
  redm[jslot][i2] = m1;      redl[jslot][i2] = l1;
  redm[jslot][i2 + 16] = m2; redl[jslot][i2 + 16] = l2;
  __syncthreads();
  float M1 = -1e30f, M2 = -1e30f;
#pragma unroll
  for (int u = 0; u < 16; u++) {
    M1 = fmaxf(M1, redm[u][i2]);
    M2 = fmaxf(M2, redm[u][i2 + 16]);
  }
  float L1 = 0.f, L2 = 0.f;
#pragma unroll
  for (int u = 0; u < 16; u++) {
    L1 += redl[u][i2] * __expf(redm[u][i2] - M1);
    L2 += redl[u][i2 + 16] * __expf(redm[u][i2 + 16] - M2);
  }
  if (jslot == 0) {
    mrow[bh * 2048 + i0 + i2] = M1;      lrow[bh * 2048 + i0 + i2] = L1;
    mrow[bh * 2048 + i0 + i2 + 16] = M2; lrow[bh * 2048 + i0 + i2 + 16] = L2;
  }
  const float invL1 = 1.0f / L1, invL2 = 1.0f / L2;

  // PV mapping: rows (ipair, ipair+16), cols dq1..dq1+3 and 64+dq1..+3
  const int ipair = t >> 4;
  const int dq1 = (t & 15) * 4;
  float acc1[8] = {0, 0, 0, 0, 0, 0, 0, 0};
  float acc2[8] = {0, 0, 0, 0, 0, 0, 0, 0};
  for (int jc = 0; jc < 2048; jc += 32) {
    __syncthreads();
    *(float4*)((float*)kws + t * 4) = *(const float4*)(kwbase + jc * 32 + t * 4);
#pragma unroll
    for (int u = 0; u < 4; u++)
      *(float4*)((float*)vs + u * 1024 + t * 4) =
          *(const float4*)(vbase + jc * 128 + u * 1024 + t * 4);
    __syncthreads();
#pragma unroll
    for (int u = 0; u < 2; u++) {
      int jl = jslot * 2 + u;
      float da = 0.f, db = 0.f;
#pragma unroll
      for (int sq = 0; sq < 8; sq++) {
        float4 kv = *(const float4*)&kws[jl][sq * 4];
        da += qva[sq].x * kv.x + qva[sq].y * kv.y + qva[sq].z * kv.z + qva[sq].w * kv.w;
        db += qvb[sq].x * kv.x + qvb[sq].y * kv.y + qvb[sq].z * kv.z + qvb[sq].w * kv.w;
      }
      ps[jl][i2] = __expf(da * invT - M1) * invL1;
      ps[jl][i2 + 16] = __expf(db * invT - M2) * invL2;
    }
    __syncthreads();
#pragma unroll
    for (int jl = 0; jl < 32; jl++) {
      float pa = ps[jl][ipair];
      float pb = ps[jl][ipair + 16];
      float4 v0 = *(const float4*)&vs[jl][dq1];
      float4 v1 = *(const float4*)&vs[jl][64 + dq1];
      acc1[0] += pa * v0.x; acc1[1] += pa * v0.y; acc1[2] += pa * v0.z; acc1[3] += pa * v0.w;
      acc1[4] += pa * v1.x; acc1[5] += pa * v1.y; acc1[6] += pa * v1.z; acc1[7] += pa * v1.w;
      acc2[0] += pb * v0.x; acc2[1] += pb * v0.y; acc2[2] += pb * v0.z; acc2[3] += pb * v0.w;
      acc2[4] += pb * v1.x; acc2[5] += pb * v1.y; acc2[6] += pb * v1.z; acc2[7] += pb * v1.w;
    }
  }
  float* o1 = aout + (b * 2048 + i0 + ipair) * 1024 + h * 128;
  float* o2 = aout + (b * 2048 + i0 + ipair + 16) * 1024 + h * 128;
  *(float4*)(o1 + dq1) = make_float4(acc1[0], acc1[1], acc1[2], acc1[3]);
  *(float4*)(o1 + 64 + dq1) = make_float4(acc1[4], acc1[5], acc1[6], acc1[7]);
  *(float4*)(o2 + dq1) = make_float4(acc2[0], acc2[1], acc2[2], acc2[3]);
  *(float4*)(o2 + 64 + dq1) = make_float4(acc2[4], acc2[5], acc2[6], acc2[7]);
}

// ---------------------------------------------------------------------------
// Attention write: recompute p = exp(qa.kw/temp - M)/L and write bijh layout.
// Block = (b, 32 i-rows, 32 j-cols, ALL 8 h)  ->  writes are dense within the
// block's (i, j, h) region, so L2 merges them into full lines.
// Thread: h = t&7 (fixed), i = t>>3 (fixed), loops jl = 0..31.
// ---------------------------------------------------------------------------
__global__ __launch_bounds__(256) void attn_write(
    const float* __restrict__ qa, const float* __restrict__ kw,
    const float* __restrict__ mrow, const float* __restrict__ lrow,
    const float* __restrict__ temp, float* __restrict__ attn) {
  __shared__ __align__(16) float kws[8][32][32];   // 32 KB: [h][jl][s]
  const int t = threadIdx.x;
  const int bx = blockIdx.x;
  const int it = bx & 63, jt = (bx >> 6) & 63, b = bx >> 12;
  const int i0 = it * 32, jc = jt * 32;
  const float invT = 1.0f / temp[0];
#pragma unroll
  for (int u = 0; u < 8; u++) {
    int flat = u * 1024 + t * 4;
    int hh = flat >> 10, rem = flat & 1023;
    int jl = rem >> 5, s = rem & 31;
    *(float4*)((float*)kws + flat) =
        *(const float4*)(kw + ((b * 8 + hh) * 2048 + jc + jl) * 32 + s);
  }
  __syncthreads();
  const int h = t & 7, i = t >> 3;
  const float* qrow = qa + ((b * 8 + h) * 2048 + i0 + i) * 32;
  float4 qv[8];
#pragma unroll
  for (int sq = 0; sq < 8; sq++) qv[sq] = *(const float4*)(qrow + sq * 4);
  const float M = mrow[(b * 8 + h) * 2048 + i0 + i];
  const float invL = 1.0f / lrow[(b * 8 + h) * 2048 + i0 + i];
  float* obase = attn + ((b * 2048 + i0 + i) * 2048 + jc) * 8 + h;
#pragma unroll
  for (int jl = 0; jl < 32; jl++) {
    float d = 0.f;
#pragma unroll
    for (int sq = 0; sq < 8; sq++) {
      float4 kv = *(const float4*)&kws[h][jl][sq * 4];
      d += qv[sq].x * kv.x + qv[sq].y * kv.y + qv[sq].z * kv.z + qv[sq].w * kv.w;
    }
    obase[jl * 8] = __expf(d * invT - M) * invL;
  }
}

// ---------------------------------------------------------------------------
extern "C" void kernel_launch(void* const* d_in, const int* in_sizes, int n_in,
                              void* d_out, int out_size, void* d_ws, size_t ws_size,
                              hipStream_t stream) {
  const float* x    = (const float*)d_in[0];
  const float* Wqkv = (const float*)d_in[1];
  const float* bqkv = (const float*)d_in[2];
  const float* Wout = (const float*)d_in[3];
  const float* bout = (const float*)d_in[4];
  const float* ctr  = (const float*)d_in[5];
  const float* ls   = (const float*)d_in[6];
  const float* la   = (const float*)d_in[7];
  const float* temp = (const float*)d_in[8];

  float* out = (float*)d_out;                 // (B,T,D) = 4,194,304 floats
  float* attn = out + 4194304;                // (B,T,T,H) = 67,108,864 floats

  float* ws = (float*)d_ws;
  float* qT   = ws;
  float* kT   = qT + 4194304;
  float* vT   = kT + 4194304;
  float* qaW  = vT + 4194304;
  float* kwW  = qaW + 1048576;
  float* mrow = kwW + 1048576;
  float* lrow = mrow + 32768;
  float* aout = lrow + 32768;

  gemm_f32<3072, true><<<dim3(24, 32), 256, 0, stream>>>(x, Wqkv, bqkv, qT, kT, vT);
  splat_weights<<<dim3(4096, 2), 256, 0, stream>>>(qT, kT, ctr, ls, la, qaW, kwW);
  attn_mlpv<<<1024, 256, 0, stream>>>(qaW, kwW, vT, temp, mrow, lrow, aout);
  attn_write<<<8192, 256, 0, stream>>>(qaW, kwW, mrow, lrow, temp, attn);
  gemm_f32<1024, false><<<dim3(8, 32), 256, 0, stream>>>(aout, Wout, bout, out, nullptr, nullptr);
}

// Round 2
// 1490.443 us; speedup vs baseline: 1.2557x; 1.2557x over previous
//
#include <hip/hip_runtime.h>
#include <math.h>

// Shapes: B=2, T=2048, D=1024, H=8, S=32, Dh=128, 3D=3072, B*T=4096
// ws layout (float offsets):
//   qT[2][8][2048][128]   @ 0          (4,194,304)  fp32, dead after splat;
//                                      vt16 (bf16 [b][h][dh][t], 4.2M shorts) aliases it
//   kT                    @ 4,194,304  (4,194,304)  fp32
//   vT                    @ 8,388,608  (4,194,304)  fp32 [b][h][t][dh]
//   qa16[2][8][2048][32]  @ 12,582,912 (524,288 fl) bf16
//   kw16                  @ 13,107,200 (524,288 fl) bf16
//   mrow[2][8][2048]      @ 13,631,488 (32,768)
//   lrow                  @ 13,664,256 (32,768)
//   aout[4096][1024]      @ 13,697,024 (4,194,304)  fp32
// total 17,891,328 floats = 71.6 MB

typedef __attribute__((ext_vector_type(8))) short s16x8;
typedef __attribute__((ext_vector_type(4))) short s16x4;
typedef __attribute__((ext_vector_type(4))) float f32x4;

__device__ inline short f2bf(float f) {
  union { float f; unsigned u; } v; v.f = f;
  unsigned r = v.u + 0x7FFFu + ((v.u >> 16) & 1u);
  return (short)(r >> 16);
}
__device__ inline float bf2f(short s) {
  union { unsigned u; float f; } v;
  v.u = ((unsigned)(unsigned short)s) << 16;
  return v.f;
}
#define MFMA_BF16(a, b, c) __builtin_amdgcn_mfma_f32_16x16x32_bf16((a), (b), (c), 0, 0, 0)

// ---------------------------------------------------------------------------
// GEMM fp32 (unchanged from round 1): C = A(4096x1024) @ W(1024xN) + bias.
// ---------------------------------------------------------------------------
template <int N, bool SCATTER>
__global__ __launch_bounds__(256) void gemm_f32(
    const float* __restrict__ A, const float* __restrict__ W,
    const float* __restrict__ bias,
    float* __restrict__ out0, float* __restrict__ out1, float* __restrict__ out2) {
  __shared__ __align__(16) float As[16][128];
  __shared__ __align__(16) float Bs[16][128];
  const int t = threadIdx.x;
  const int col0 = blockIdx.x * 128;
  const int row0 = blockIdx.y * 128;
  const int tm = t & 15, tn = t >> 4;
  const int K = 1024;
  float acc[8][8];
#pragma unroll
  for (int i = 0; i < 8; i++)
#pragma unroll
    for (int j = 0; j < 8; j++) acc[i][j] = 0.f;

  const int am = t & 127, ak = (t >> 7) * 8;
  const int bk = t >> 4, bn = (t & 15) * 8;

  for (int k0 = 0; k0 < K; k0 += 16) {
    float4 a0 = *(const float4*)(A + (row0 + am) * K + k0 + ak);
    float4 a1 = *(const float4*)(A + (row0 + am) * K + k0 + ak + 4);
    float4 b0 = *(const float4*)(W + (k0 + bk) * N + col0 + bn);
    float4 b1 = *(const float4*)(W + (k0 + bk) * N + col0 + bn + 4);
    __syncthreads();
    As[ak + 0][am] = a0.x; As[ak + 1][am] = a0.y;
    As[ak + 2][am] = a0.z; As[ak + 3][am] = a0.w;
    As[ak + 4][am] = a1.x; As[ak + 5][am] = a1.y;
    As[ak + 6][am] = a1.z; As[ak + 7][am] = a1.w;
    *(float4*)&Bs[bk][bn] = b0;
    *(float4*)&Bs[bk][bn + 4] = b1;
    __syncthreads();
#pragma unroll
    for (int kk = 0; kk < 16; kk++) {
      float4 av0 = *(const float4*)&As[kk][tm * 4];
      float4 av1 = *(const float4*)&As[kk][64 + tm * 4];
      float4 bv0 = *(const float4*)&Bs[kk][tn * 4];
      float4 bv1 = *(const float4*)&Bs[kk][64 + tn * 4];
      float a_[8] = {av0.x, av0.y, av0.z, av0.w, av1.x, av1.y, av1.z, av1.w};
      float b_[8] = {bv0.x, bv0.y, bv0.z, bv0.w, bv1.x, bv1.y, bv1.z, bv1.w};
#pragma unroll
      for (int i = 0; i < 8; i++)
#pragma unroll
        for (int j = 0; j < 8; j++) acc[i][j] += a_[i] * b_[j];
    }
  }
#pragma unroll
  for (int hi = 0; hi < 2; hi++) {
#pragma unroll
    for (int ii = 0; ii < 4; ii++) {
      int row = row0 + hi * 64 + tm * 4 + ii;
#pragma unroll
      for (int hj = 0; hj < 2; hj++) {
#pragma unroll
        for (int jj = 0; jj < 4; jj++) {
          int col = col0 + hj * 64 + tn * 4 + jj;
          float v = acc[hi * 4 + ii][hj * 4 + jj] + bias[col];
          if (SCATTER) {
            int three = col >> 10;
            int h = (col >> 7) & 7;
            int dh = col & 127;
            int bb = row >> 11, tt = row & 2047;
            float* dst = (three == 0) ? out0 : ((three == 1) ? out1 : out2);
            dst[((bb * 8 + h) * 2048 + tt) * 128 + dh] = v;
          } else {
            out0[row * N + col] = v;
          }
        }
      }
    }
  }
}

// ---------------------------------------------------------------------------
// Splat weights -> bf16 qa/kw, layout [b][h][t][s].
// ---------------------------------------------------------------------------
__global__ __launch_bounds__(256) void splat_weights(
    const float* __restrict__ qT, const float* __restrict__ kT,
    const float* __restrict__ ctr, const float* __restrict__ ls,
    const float* __restrict__ la, short* __restrict__ qa16, short* __restrict__ kw16) {
  const int bt = blockIdx.x;
  const int which = blockIdx.y;
  const int b = bt >> 11, tt = bt & 2047;
  const float* src = which ? kT : qT;
  __shared__ __align__(16) float rowbuf[1024];
  {
    int flat = threadIdx.x * 4;
    int hh = flat >> 7, d = flat & 127;
    *(float4*)&rowbuf[flat] = *(const float4*)(src + ((b * 8 + hh) * 2048 + tt) * 128 + d);
  }
  __syncthreads();
  const int h = threadIdx.x >> 5, s = threadIdx.x & 31;
  const float* c = ctr + (h * 32 + s) * 128;
  const float* qr = &rowbuf[h * 128];
  float qsq = 0.f, csq = 0.f, dot = 0.f;
#pragma unroll
  for (int u = 0; u < 32; u++) {
    float4 cv = *(const float4*)(c + u * 4);
    float4 qv = *(const float4*)(qr + u * 4);
    qsq += qv.x * qv.x + qv.y * qv.y + qv.z * qv.z + qv.w * qv.w;
    csq += cv.x * cv.x + cv.y * cv.y + cv.z * cv.z + cv.w * cv.w;
    dot += qv.x * cv.x + qv.y * cv.y + qv.z * cv.z + qv.w * cv.w;
  }
  float d2 = fmaxf(qsq + csq - 2.f * dot, 0.f);
  float scale = __expf(ls[h * 32 + s]);
  float inv = 1.0f / (scale + 1e-6f);
  float w = __expf(-0.5f * d2 * inv * inv);
  if (which == 0) w *= __expf(la[h * 32 + s]);
  short* dst = which ? kw16 : qa16;
  dst[((b * 8 + h) * 2048 + tt) * 32 + s] = f2bf(w);
}

// ---------------------------------------------------------------------------
// V transpose: vT fp32 [b][h][t][dh] -> vt16 bf16 [b][h][dh][t]
// ---------------------------------------------------------------------------
__global__ __launch_bounds__(256) void transpose_v(
    const float* __restrict__ vT, short* __restrict__ vt16) {
  __shared__ float tile[32][33];
  const int t0 = blockIdx.x * 32, d0 = blockIdx.y * 32, bh = blockIdx.z;
  const int r = threadIdx.x >> 3, c4 = (threadIdx.x & 7) * 4;
  float4 v = *(const float4*)(vT + ((size_t)(bh * 2048 + t0 + r)) * 128 + d0 + c4);
  tile[r][c4 + 0] = v.x; tile[r][c4 + 1] = v.y;
  tile[r][c4 + 2] = v.z; tile[r][c4 + 3] = v.w;
  __syncthreads();
  s16x4 o;
  o[0] = f2bf(tile[c4 + 0][r]);
  o[1] = f2bf(tile[c4 + 1][r]);
  o[2] = f2bf(tile[c4 + 2][r]);
  o[3] = f2bf(tile[c4 + 3][r]);
  *(s16x4*)(vt16 + ((size_t)(bh * 128 + d0 + r)) * 2048 + t0 + c4) = o;
}

// ---------------------------------------------------------------------------
// Flash attention with MFMA. Block = 256 thr = 4 waves; wave owns 16 i-rows.
// Grid (T/64, H, B). No barriers: frags load straight from global (L2-hot),
// P does a per-wave LDS round-trip (C-layout -> A-layout).
// Writes mrow/lrow (for attn_write) and aout fp32 (B*T, D).
// ---------------------------------------------------------------------------
__global__ __launch_bounds__(256) void attn_flash(
    const short* __restrict__ qa16, const short* __restrict__ kw16,
    const short* __restrict__ vt16, const float* __restrict__ temp,
    float* __restrict__ mrow, float* __restrict__ lrow,
    float* __restrict__ aout) {
  __shared__ float pads[4][16][36];
  const int tid = threadIdx.x;
  const int w = tid >> 6, l = tid & 63;
  const int lm = l & 15, lk = l >> 4;
  const int it = blockIdx.x, h = blockIdx.y, b = blockIdx.z;
  const int bh = b * 8 + h;
  const int i0 = it * 64 + w * 16;
  const float invT = 1.0f / temp[0];
  const short* kwb = kw16 + (size_t)bh * 2048 * 32;
  const short* vtb = vt16 + (size_t)bh * 128 * 2048;
  // A-frag of qa: A[m=lm][k=lk*8+j]
  s16x8 qfrag = *(const s16x8*)(qa16 + ((size_t)(bh * 2048 + i0 + lm)) * 32 + lk * 8);
  float m_i[4] = {-1e30f, -1e30f, -1e30f, -1e30f};
  float l_i[4] = {0.f, 0.f, 0.f, 0.f};
  f32x4 acc[8];
#pragma unroll
  for (int d = 0; d < 8; d++) acc[d] = (f32x4){0.f, 0.f, 0.f, 0.f};
  float (*pw)[36] = pads[w];

  for (int jc = 0; jc < 2048; jc += 32) {
    // logits S[i][j], j-chunk of 32 as two 16-col MFMAs.  B[k=s][n=j]=kw[j][s]
    s16x8 kb0 = *(const s16x8*)(kwb + (size_t)(jc + lm) * 32 + lk * 8);
    s16x8 kb1 = *(const s16x8*)(kwb + (size_t)(jc + 16 + lm) * 32 + lk * 8);
    f32x4 z = (f32x4){0.f, 0.f, 0.f, 0.f};
    f32x4 s0 = MFMA_BF16(qfrag, kb0, z);
    f32x4 s1 = MFMA_BF16(qfrag, kb1, z);
    float p0[4], p1[4], alpha[4];
#pragma unroll
    for (int r = 0; r < 4; r++) {
      float a = s0[r] * invT, bb = s1[r] * invT;
      float cm = fmaxf(a, bb);
      cm = fmaxf(cm, __shfl_xor(cm, 1));
      cm = fmaxf(cm, __shfl_xor(cm, 2));
      cm = fmaxf(cm, __shfl_xor(cm, 4));
      cm = fmaxf(cm, __shfl_xor(cm, 8));
      float mn = fmaxf(m_i[r], cm);
      alpha[r] = __expf(m_i[r] - mn);
      m_i[r] = mn;
      p0[r] = __expf(a - mn);
      p1[r] = __expf(bb - mn);
      float rs = p0[r] + p1[r];
      rs += __shfl_xor(rs, 1);
      rs += __shfl_xor(rs, 2);
      rs += __shfl_xor(rs, 4);
      rs += __shfl_xor(rs, 8);
      l_i[r] = l_i[r] * alpha[r] + rs;
    }
#pragma unroll
    for (int d = 0; d < 8; d++)
#pragma unroll
      for (int r = 0; r < 4; r++) acc[d][r] *= alpha[r];
    // P: C-layout (row=lk*4+r, col=lm) -> LDS -> A-layout (m=lm, k=lk*8+j)
#pragma unroll
    for (int r = 0; r < 4; r++) {
      pw[lk * 4 + r][lm] = p0[r];
      pw[lk * 4 + r][16 + lm] = p1[r];
    }
    s16x8 pfrag;
#pragma unroll
    for (int j = 0; j < 8; j++) pfrag[j] = f2bf(pw[lm][lk * 8 + j]);
    // PV: B[k=j][n=dh] = vt[dh][j]
#pragma unroll
    for (int d = 0; d < 8; d++) {
      s16x8 vb = *(const s16x8*)(vtb + (size_t)(d * 16 + lm) * 2048 + jc + lk * 8);
      acc[d] = MFMA_BF16(pfrag, vb, acc[d]);
    }
  }
  float invl[4];
#pragma unroll
  for (int r = 0; r < 4; r++) invl[r] = 1.0f / l_i[r];
#pragma unroll
  for (int r = 0; r < 4; r++) {
    int row = i0 + lk * 4 + r;
    float* ob = aout + (size_t)(b * 2048 + row) * 1024 + h * 128 + lm;
#pragma unroll
    for (int d = 0; d < 8; d++) ob[d * 16] = acc[d][r] * invl[r];
  }
  if (lm == 0) {
#pragma unroll
    for (int r = 0; r < 4; r++) {
      mrow[bh * 2048 + i0 + lk * 4 + r] = m_i[r];
      lrow[bh * 2048 + i0 + lk * 4 + r] = l_i[r];
    }
  }
}

// ---------------------------------------------------------------------------
// Attention write (bijh layout, dense per-block writes across all 8 h).
// Reads bf16 qa/kw, converts to fp32 on load; recomputes p with saved m,l.
// ---------------------------------------------------------------------------
__global__ __launch_bounds__(256) void attn_write(
    const short* __restrict__ qa16, const short* __restrict__ kw16,
    const float* __restrict__ mrow, const float* __restrict__ lrow,
    const float* __restrict__ temp, float* __restrict__ attn) {
  __shared__ float kws[8][32][32];   // 32 KB: [h][jl][s]
  const int t = threadIdx.x;
  const int bx = blockIdx.x;
  const int it = bx & 63, jt = (bx >> 6) & 63, b = bx >> 12;
  const int i0 = it * 32, jc = jt * 32;
  const float invT = 1.0f / temp[0];
#pragma unroll
  for (int u = 0; u < 4; u++) {
    int flat = u * 2048 + t * 8;       // short index within 8*32*32
    int hh = flat >> 10;
    int rem = flat & 1023;
    int jl = rem >> 5, s = rem & 31;
    s16x8 raw = *(const s16x8*)(kw16 + ((size_t)(b * 8 + hh) * 2048 + jc + jl) * 32 + s);
#pragma unroll
    for (int e = 0; e < 8; e++) kws[hh][jl][s + e] = bf2f(raw[e]);
  }
  __syncthreads();
  const int h = t & 7, i = t >> 3;
  const short* qrow16 = qa16 + ((size_t)(b * 8 + h) * 2048 + i0 + i) * 32;
  float qv[32];
#pragma unroll
  for (int sq = 0; sq < 4; sq++) {
    s16x8 raw = *(const s16x8*)(qrow16 + sq * 8);
#pragma unroll
    for (int e = 0; e < 8; e++) qv[sq * 8 + e] = bf2f(raw[e]);
  }
  const float M = mrow[(b * 8 + h) * 2048 + i0 + i];
  const float invL = 1.0f / lrow[(b * 8 + h) * 2048 + i0 + i];
  float* obase = attn + (((size_t)(b * 2048 + i0 + i)) * 2048 + jc) * 8 + h;
#pragma unroll
  for (int jl = 0; jl < 32; jl++) {
    float d = 0.f;
#pragma unroll
    for (int sq = 0; sq < 32; sq++) d += qv[sq] * kws[h][jl][sq];
    obase[jl * 8] = __expf(d * invT - M) * invL;
  }
}

// ---------------------------------------------------------------------------
extern "C" void kernel_launch(void* const* d_in, const int* in_sizes, int n_in,
                              void* d_out, int out_size, void* d_ws, size_t ws_size,
                              hipStream_t stream) {
  const float* x    = (const float*)d_in[0];
  const float* Wqkv = (const float*)d_in[1];
  const float* bqkv = (const float*)d_in[2];
  const float* Wout = (const float*)d_in[3];
  const float* bout = (const float*)d_in[4];
  const float* ctr  = (const float*)d_in[5];
  const float* ls   = (const float*)d_in[6];
  const float* la   = (const float*)d_in[7];
  const float* temp = (const float*)d_in[8];

  float* out = (float*)d_out;                 // (B,T,D)
  float* attn = out + 4194304;                // (B,T,T,H)

  float* ws = (float*)d_ws;
  float* qT   = ws;                           // fp32, dead after splat
  float* kT   = qT + 4194304;
  float* vT   = kT + 4194304;
  short* qa16 = (short*)(vT + 4194304);       // 1,048,576 shorts
  short* kw16 = qa16 + 1048576;
  float* mrow = (float*)(kw16 + 1048576);
  float* lrow = mrow + 32768;
  float* aout = lrow + 32768;
  short* vt16 = (short*)ws;                   // aliases qT (dead by then)

  gemm_f32<3072, true><<<dim3(24, 32), 256, 0, stream>>>(x, Wqkv, bqkv, qT, kT, vT);
  splat_weights<<<dim3(4096, 2), 256, 0, stream>>>(qT, kT, ctr, ls, la, qa16, kw16);
  transpose_v<<<dim3(64, 4, 16), 256, 0, stream>>>(vT, vt16);
  attn_flash<<<dim3(32, 8, 2), 256, 0, stream>>>(qa16, kw16, vt16, temp, mrow, lrow, aout);
  attn_write<<<8192, 256, 0, stream>>>(qa16, kw16, mrow, lrow, temp, attn);
  gemm_f32<1024, false><<<dim3(8, 32), 256, 0, stream>>>(aout, Wout, bout, out, nullptr, nullptr);
}

// Round 3
// 967.320 us; speedup vs baseline: 1.9348x; 1.5408x over previous
//
#include <hip/hip_runtime.h>
#include <math.h>

// Shapes: B=2, T=2048, D=1024, H=8, S=32, Dh=128, 3D=3072, B*T=4096
// ws layout (float offsets):
//   qT fp32 [b][h][t][dh]  @ 0           (4,194,304)  dead after splat; then:
//       vt16 bf16 [b][h][dh][t] aliases shorts [0 : 4,194,304)
//       Wot16 bf16 [n][k]       aliases shorts [4,194,304 : 5,242,880)
//   kT fp32                @ 4,194,304   (4,194,304)
//   vT fp32 [b][h][t][dh]  @ 8,388,608   (4,194,304)  dead after transpose_v;
//       aout16 bf16 [m][k] aliases it (4,194,304 shorts)
//   x16 bf16 [m][k]        @ 12,582,912  (4,194,304 shorts)
//   Wqt16 bf16 [n][k]      @ +            (3,145,728 shorts)
//   qa16 [b][h][t][s]      @ +            (1,048,576 shorts)
//   kw16                   @ +            (1,048,576 shorts)
//   mrow [b][h][t]         @ +            (32,768 floats)
//   lrow                   @ +            (32,768 floats)
// total ~69.5 MB

typedef __attribute__((ext_vector_type(8))) short s16x8;
typedef __attribute__((ext_vector_type(4))) short s16x4;
typedef __attribute__((ext_vector_type(4))) float f32x4;

__device__ inline short f2bf(float f) {
  union { float f; unsigned u; } v; v.f = f;
  unsigned r = v.u + 0x7FFFu + ((v.u >> 16) & 1u);
  return (short)(r >> 16);
}
__device__ inline float bf2f(short s) {
  union { unsigned u; float f; } v;
  v.u = ((unsigned)(unsigned short)s) << 16;
  return v.f;
}
#define MFMA_BF16(a, b, c) __builtin_amdgcn_mfma_f32_16x16x32_bf16((a), (b), (c), 0, 0, 0)

// ---------------------------------------------------------------------------
// Elementwise fp32 -> bf16 cast (n4 = count/4).
// ---------------------------------------------------------------------------
__global__ __launch_bounds__(256) void cast_bf16(
    const float* __restrict__ in, short* __restrict__ out, int n4) {
  int i = blockIdx.x * 256 + threadIdx.x;
  if (i < n4) {
    float4 v = ((const float4*)in)[i];
    s16x4 o;
    o[0] = f2bf(v.x); o[1] = f2bf(v.y); o[2] = f2bf(v.z); o[3] = f2bf(v.w);
    ((s16x4*)out)[i] = o;
  }
}

// ---------------------------------------------------------------------------
// W[K][N] fp32 -> Wt[N][K] bf16.  grid (N/32, K/32), block 256.
// ---------------------------------------------------------------------------
__global__ __launch_bounds__(256) void transpose_cast(
    const float* __restrict__ W, short* __restrict__ Wt, int K, int N) {
  __shared__ float tile[32][33];
  const int n0 = blockIdx.x * 32, k0 = blockIdx.y * 32;
  const int r = threadIdx.x >> 3, c4 = (threadIdx.x & 7) * 4;
  float4 v = *(const float4*)(W + (size_t)(k0 + r) * N + n0 + c4);
  tile[r][c4 + 0] = v.x; tile[r][c4 + 1] = v.y;
  tile[r][c4 + 2] = v.z; tile[r][c4 + 3] = v.w;
  __syncthreads();
  s16x4 o;
  o[0] = f2bf(tile[c4 + 0][r]);
  o[1] = f2bf(tile[c4 + 1][r]);
  o[2] = f2bf(tile[c4 + 2][r]);
  o[3] = f2bf(tile[c4 + 3][r]);
  *(s16x4*)(Wt + (size_t)(n0 + r) * K + k0 + c4) = o;
}

// ---------------------------------------------------------------------------
// bf16 MFMA GEMM: C[m][n] = A16[m][k] @ Wt16[n][k]^T + bias[n], M=4096, K=1024.
// Block = 4 waves, 128x128 tile; wave = 64x64 (4x4 MFMAs of 16x16x32).
// No LDS: fragments load straight from global (L2-hot).
// SCATTER: N=3072, scatter fp32 into qT/kT/vT [b][h][t][dh]; else out0[m*N+n].
// ---------------------------------------------------------------------------
template <int N, bool SCATTER>
__global__ __launch_bounds__(256) void gemm_bf16(
    const short* __restrict__ A, const short* __restrict__ Wt,
    const float* __restrict__ bias,
    float* __restrict__ out0, float* __restrict__ out1, float* __restrict__ out2) {
  const int tid = threadIdx.x;
  const int w = tid >> 6, l = tid & 63;
  const int lm = l & 15, lk = l >> 4;
  const int n0 = blockIdx.x * 128 + (w & 1) * 64;
  const int m0 = blockIdx.y * 128 + (w >> 1) * 64;
  const int K = 1024;
  f32x4 acc[4][4];
#pragma unroll
  for (int mi = 0; mi < 4; mi++)
#pragma unroll
    for (int ni = 0; ni < 4; ni++) acc[mi][ni] = (f32x4){0.f, 0.f, 0.f, 0.f};

  for (int k0 = 0; k0 < K; k0 += 32) {
    s16x8 af[4], bf[4];
#pragma unroll
    for (int mi = 0; mi < 4; mi++)
      af[mi] = *(const s16x8*)(A + (size_t)(m0 + mi * 16 + lm) * K + k0 + lk * 8);
#pragma unroll
    for (int ni = 0; ni < 4; ni++)
      bf[ni] = *(const s16x8*)(Wt + (size_t)(n0 + ni * 16 + lm) * K + k0 + lk * 8);
#pragma unroll
    for (int mi = 0; mi < 4; mi++)
#pragma unroll
      for (int ni = 0; ni < 4; ni++)
        acc[mi][ni] = MFMA_BF16(af[mi], bf[ni], acc[mi][ni]);
  }
#pragma unroll
  for (int ni = 0; ni < 4; ni++) {
    const int n = n0 + ni * 16 + lm;
    const float bv = bias[n];
#pragma unroll
    for (int mi = 0; mi < 4; mi++) {
#pragma unroll
      for (int r = 0; r < 4; r++) {
        const int m = m0 + mi * 16 + lk * 4 + r;
        float v = acc[mi][ni][r] + bv;
        if (SCATTER) {
          int three = n >> 10;
          int h = (n >> 7) & 7;
          int dh = n & 127;
          int bb = m >> 11, tt = m & 2047;
          float* dst = (three == 0) ? out0 : ((three == 1) ? out1 : out2);
          dst[((size_t)(bb * 8 + h) * 2048 + tt) * 128 + dh] = v;
        } else {
          out0[(size_t)m * N + n] = v;
        }
      }
    }
  }
}

// ---------------------------------------------------------------------------
// Splat weights -> bf16 qa/kw, layout [b][h][t][s].
// ---------------------------------------------------------------------------
__global__ __launch_bounds__(256) void splat_weights(
    const float* __restrict__ qT, const float* __restrict__ kT,
    const float* __restrict__ ctr, const float* __restrict__ ls,
    const float* __restrict__ la, short* __restrict__ qa16, short* __restrict__ kw16) {
  const int bt = blockIdx.x;
  const int which = blockIdx.y;
  const int b = bt >> 11, tt = bt & 2047;
  const float* src = which ? kT : qT;
  __shared__ __align__(16) float rowbuf[1024];
  {
    int flat = threadIdx.x * 4;
    int hh = flat >> 7, d = flat & 127;
    *(float4*)&rowbuf[flat] = *(const float4*)(src + ((size_t)(b * 8 + hh) * 2048 + tt) * 128 + d);
  }
  __syncthreads();
  const int h = threadIdx.x >> 5, s = threadIdx.x & 31;
  const float* c = ctr + (h * 32 + s) * 128;
  const float* qr = &rowbuf[h * 128];
  float qsq = 0.f, csq = 0.f, dot = 0.f;
#pragma unroll
  for (int u = 0; u < 32; u++) {
    float4 cv = *(const float4*)(c + u * 4);
    float4 qv = *(const float4*)(qr + u * 4);
    qsq += qv.x * qv.x + qv.y * qv.y + qv.z * qv.z + qv.w * qv.w;
    csq += cv.x * cv.x + cv.y * cv.y + cv.z * cv.z + cv.w * cv.w;
    dot += qv.x * cv.x + qv.y * cv.y + qv.z * cv.z + qv.w * cv.w;
  }
  float d2 = fmaxf(qsq + csq - 2.f * dot, 0.f);
  float scale = __expf(ls[h * 32 + s]);
  float inv = 1.0f / (scale + 1e-6f);
  float w = __expf(-0.5f * d2 * inv * inv);
  if (which == 0) w *= __expf(la[h * 32 + s]);
  short* dst = which ? kw16 : qa16;
  dst[((size_t)(b * 8 + h) * 2048 + tt) * 32 + s] = f2bf(w);
}

// ---------------------------------------------------------------------------
// V transpose: vT fp32 [b][h][t][dh] -> vt16 bf16 [b][h][dh][t]
// ---------------------------------------------------------------------------
__global__ __launch_bounds__(256) void transpose_v(
    const float* __restrict__ vT, short* __restrict__ vt16) {
  __shared__ float tile[32][33];
  const int t0 = blockIdx.x * 32, d0 = blockIdx.y * 32, bh = blockIdx.z;
  const int r = threadIdx.x >> 3, c4 = (threadIdx.x & 7) * 4;
  float4 v = *(const float4*)(vT + ((size_t)(bh * 2048 + t0 + r)) * 128 + d0 + c4);
  tile[r][c4 + 0] = v.x; tile[r][c4 + 1] = v.y;
  tile[r][c4 + 2] = v.z; tile[r][c4 + 3] = v.w;
  __syncthreads();
  s16x4 o;
  o[0] = f2bf(tile[c4 + 0][r]);
  o[1] = f2bf(tile[c4 + 1][r]);
  o[2] = f2bf(tile[c4 + 2][r]);
  o[3] = f2bf(tile[c4 + 3][r]);
  *(s16x4*)(vt16 + ((size_t)(bh * 128 + d0 + r)) * 2048 + t0 + c4) = o;
}

// ---------------------------------------------------------------------------
// Flash attention with MFMA. Block = 256 thr = 4 waves; wave owns 16 i-rows.
// Writes mrow/lrow and aout16 (bf16, [b*T][D]) = attention @ V.
// ---------------------------------------------------------------------------
__global__ __launch_bounds__(256) void attn_flash(
    const short* __restrict__ qa16, const short* __restrict__ kw16,
    const short* __restrict__ vt16, const float* __restrict__ temp,
    float* __restrict__ mrow, float* __restrict__ lrow,
    short* __restrict__ aout16) {
  __shared__ float pads[4][16][36];
  const int tid = threadIdx.x;
  const int w = tid >> 6, l = tid & 63;
  const int lm = l & 15, lk = l >> 4;
  const int it = blockIdx.x, h = blockIdx.y, b = blockIdx.z;
  const int bh = b * 8 + h;
  const int i0 = it * 64 + w * 16;
  const float invT = 1.0f / temp[0];
  const short* kwb = kw16 + (size_t)bh * 2048 * 32;
  const short* vtb = vt16 + (size_t)bh * 128 * 2048;
  s16x8 qfrag = *(const s16x8*)(qa16 + ((size_t)(bh * 2048 + i0 + lm)) * 32 + lk * 8);
  float m_i[4] = {-1e30f, -1e30f, -1e30f, -1e30f};
  float l_i[4] = {0.f, 0.f, 0.f, 0.f};
  f32x4 acc[8];
#pragma unroll
  for (int d = 0; d < 8; d++) acc[d] = (f32x4){0.f, 0.f, 0.f, 0.f};
  float (*pw)[36] = pads[w];

  for (int jc = 0; jc < 2048; jc += 32) {
    s16x8 kb0 = *(const s16x8*)(kwb + (size_t)(jc + lm) * 32 + lk * 8);
    s16x8 kb1 = *(const s16x8*)(kwb + (size_t)(jc + 16 + lm) * 32 + lk * 8);
    f32x4 z = (f32x4){0.f, 0.f, 0.f, 0.f};
    f32x4 s0 = MFMA_BF16(qfrag, kb0, z);
    f32x4 s1 = MFMA_BF16(qfrag, kb1, z);
    float p0[4], p1[4], alpha[4];
#pragma unroll
    for (int r = 0; r < 4; r++) {
      float a = s0[r] * invT, bb = s1[r] * invT;
      float cm = fmaxf(a, bb);
      cm = fmaxf(cm, __shfl_xor(cm, 1));
      cm = fmaxf(cm, __shfl_xor(cm, 2));
      cm = fmaxf(cm, __shfl_xor(cm, 4));
      cm = fmaxf(cm, __shfl_xor(cm, 8));
      float mn = fmaxf(m_i[r], cm);
      alpha[r] = __expf(m_i[r] - mn);
      m_i[r] = mn;
      p0[r] = __expf(a - mn);
      p1[r] = __expf(bb - mn);
      float rs = p0[r] + p1[r];
      rs += __shfl_xor(rs, 1);
      rs += __shfl_xor(rs, 2);
      rs += __shfl_xor(rs, 4);
      rs += __shfl_xor(rs, 8);
      l_i[r] = l_i[r] * alpha[r] + rs;
    }
#pragma unroll
    for (int d = 0; d < 8; d++)
#pragma unroll
      for (int r = 0; r < 4; r++) acc[d][r] *= alpha[r];
#pragma unroll
    for (int r = 0; r < 4; r++) {
      pw[lk * 4 + r][lm] = p0[r];
      pw[lk * 4 + r][16 + lm] = p1[r];
    }
    s16x8 pfrag;
#pragma unroll
    for (int j = 0; j < 8; j++) pfrag[j] = f2bf(pw[lm][lk * 8 + j]);
#pragma unroll
    for (int d = 0; d < 8; d++) {
      s16x8 vb = *(const s16x8*)(vtb + (size_t)(d * 16 + lm) * 2048 + jc + lk * 8);
      acc[d] = MFMA_BF16(pfrag, vb, acc[d]);
    }
  }
  float invl[4];
#pragma unroll
  for (int r = 0; r < 4; r++) invl[r] = 1.0f / l_i[r];
#pragma unroll
  for (int r = 0; r < 4; r++) {
    int row = i0 + lk * 4 + r;
    short* ob = aout16 + (size_t)(b * 2048 + row) * 1024 + h * 128 + lm;
#pragma unroll
    for (int d = 0; d < 8; d++) ob[d * 16] = f2bf(acc[d][r] * invl[r]);
  }
  if (lm == 0) {
#pragma unroll
    for (int r = 0; r < 4; r++) {
      mrow[bh * 2048 + i0 + lk * 4 + r] = m_i[r];
      lrow[bh * 2048 + i0 + lk * 4 + r] = l_i[r];
    }
  }
}

// ---------------------------------------------------------------------------
// Attention write v2: MFMA recompute, NO LDS, direct scalar global stores.
// Block = (b, 32 i-rows, 32 j-cols), 4 waves; wave w handles h = 2w, 2w+1.
// For each h: 4 MFMAs (2 i-halves x 2 j-halves), p = exp(s/T - M)/L,
// scatter-store into attn[b][i][j][h] (L2 merges the stride-8 scalars).
// ---------------------------------------------------------------------------
__global__ __launch_bounds__(256) void attn_write(
    const short* __restrict__ qa16, const short* __restrict__ kw16,
    const float* __restrict__ mrow, const float* __restrict__ lrow,
    const float* __restrict__ temp, float* __restrict__ attn) {
  const int tid = threadIdx.x;
  const int w = tid >> 6, l = tid & 63;
  const int lm = l & 15, lk = l >> 4;
  const int i0 = blockIdx.x * 32, j0 = blockIdx.y * 32, b = blockIdx.z;
  const float invT = 1.0f / temp[0];
#pragma unroll
  for (int hh = 0; hh < 2; hh++) {
    const int h = w * 2 + hh;
    const int bh = b * 8 + h;
    s16x8 qf[2], kf[2];
#pragma unroll
    for (int ih = 0; ih < 2; ih++)
      qf[ih] = *(const s16x8*)(qa16 + ((size_t)(bh * 2048 + i0 + ih * 16 + lm)) * 32 + lk * 8);
#pragma unroll
    for (int jh = 0; jh < 2; jh++)
      kf[jh] = *(const s16x8*)(kw16 + ((size_t)(bh * 2048 + j0 + jh * 16 + lm)) * 32 + lk * 8);
    float mv[2][4], il[2][4];
#pragma unroll
    for (int ih = 0; ih < 2; ih++)
#pragma unroll
      for (int r = 0; r < 4; r++) {
        int i = i0 + ih * 16 + lk * 4 + r;
        mv[ih][r] = mrow[bh * 2048 + i];
        il[ih][r] = 1.0f / lrow[bh * 2048 + i];
      }
    f32x4 z = (f32x4){0.f, 0.f, 0.f, 0.f};
#pragma unroll
    for (int ih = 0; ih < 2; ih++) {
#pragma unroll
      for (int jh = 0; jh < 2; jh++) {
        f32x4 s = MFMA_BF16(qf[ih], kf[jh], z);
#pragma unroll
        for (int r = 0; r < 4; r++) {
          float p = __expf(s[r] * invT - mv[ih][r]) * il[ih][r];
          int i = i0 + ih * 16 + lk * 4 + r;
          int j = j0 + jh * 16 + lm;
          attn[(((size_t)(b * 2048 + i)) * 2048 + j) * 8 + h] = p;
        }
      }
    }
  }
}

// ---------------------------------------------------------------------------
extern "C" void kernel_launch(void* const* d_in, const int* in_sizes, int n_in,
                              void* d_out, int out_size, void* d_ws, size_t ws_size,
                              hipStream_t stream) {
  const float* x    = (const float*)d_in[0];
  const float* Wqkv = (const float*)d_in[1];
  const float* bqkv = (const float*)d_in[2];
  const float* Wout = (const float*)d_in[3];
  const float* bout = (const float*)d_in[4];
  const float* ctr  = (const float*)d_in[5];
  const float* ls   = (const float*)d_in[6];
  const float* la   = (const float*)d_in[7];
  const float* temp = (const float*)d_in[8];

  float* out = (float*)d_out;                 // (B,T,D)
  float* attn = out + 4194304;                // (B,T,T,H)

  float* ws = (float*)d_ws;
  float* qT    = ws;                          // 4,194,304 fp32
  float* kT    = qT + 4194304;
  float* vT    = kT + 4194304;
  short* x16   = (short*)(vT + 4194304);      // 4,194,304 shorts
  short* Wqt16 = x16 + 4194304;               // 3,145,728 shorts
  short* qa16  = Wqt16 + 3145728;             // 1,048,576 shorts
  short* kw16  = qa16 + 1048576;
  float* mrow  = (float*)(kw16 + 1048576);    // 32,768 fp32
  float* lrow  = mrow + 32768;
  short* vt16  = (short*)ws;                  // aliases qT[0:8MB]   (after splat)
  short* Wot16 = (short*)ws + 4194304;        // aliases qT[8:10MB]  (after splat)
  short* aout16 = (short*)vT;                 // aliases vT          (after transpose_v)

  cast_bf16<<<4096, 256, 0, stream>>>(x, x16, 1048576);
  transpose_cast<<<dim3(96, 32), 256, 0, stream>>>(Wqkv, Wqt16, 1024, 3072);
  gemm_bf16<3072, true><<<dim3(24, 32), 256, 0, stream>>>(x16, Wqt16, bqkv, qT, kT, vT);
  splat_weights<<<dim3(4096, 2), 256, 0, stream>>>(qT, kT, ctr, ls, la, qa16, kw16);
  transpose_v<<<dim3(64, 4, 16), 256, 0, stream>>>(vT, vt16);
  transpose_cast<<<dim3(32, 32), 256, 0, stream>>>(Wout, Wot16, 1024, 1024);
  attn_flash<<<dim3(32, 8, 2), 256, 0, stream>>>(qa16, kw16, vt16, temp, mrow, lrow, aout16);
  attn_write<<<dim3(64, 64, 2), 256, 0, stream>>>(qa16, kw16, mrow, lrow, temp, attn);
  gemm_bf16<1024, false><<<dim3(8, 32), 256, 0, stream>>>(aout16, Wot16, bout, out, nullptr, nullptr);
}

// Round 4
// 815.561 us; speedup vs baseline: 2.2948x; 1.1861x over previous
//
#include <hip/hip_runtime.h>
#include <math.h>

// Shapes: B=2, T=2048, D=1024, H=8, S=32, Dh=128, 3D=3072, B*T=4096
// ws layout identical to round 3.

typedef __attribute__((ext_vector_type(8))) short s16x8;
typedef __attribute__((ext_vector_type(4))) short s16x4;
typedef __attribute__((ext_vector_type(4))) float f32x4;

__device__ inline short f2bf(float f) {
  union { float f; unsigned u; } v; v.f = f;
  unsigned r = v.u + 0x7FFFu + ((v.u >> 16) & 1u);
  return (short)(r >> 16);
}
__device__ inline float bf2f(short s) {
  union { unsigned u; float f; } v;
  v.u = ((unsigned)(unsigned short)s) << 16;
  return v.f;
}
#define MFMA_BF16(a, b, c) __builtin_amdgcn_mfma_f32_16x16x32_bf16((a), (b), (c), 0, 0, 0)

// ---------------------------------------------------------------------------
// Elementwise fp32 -> bf16 cast (n4 = count/4).
// ---------------------------------------------------------------------------
__global__ __launch_bounds__(256) void cast_bf16(
    const float* __restrict__ in, short* __restrict__ out, int n4) {
  int i = blockIdx.x * 256 + threadIdx.x;
  if (i < n4) {
    float4 v = ((const float4*)in)[i];
    s16x4 o;
    o[0] = f2bf(v.x); o[1] = f2bf(v.y); o[2] = f2bf(v.z); o[3] = f2bf(v.w);
    ((s16x4*)out)[i] = o;
  }
}

// ---------------------------------------------------------------------------
// W[K][N] fp32 -> Wt[N][K] bf16.  grid (N/32, K/32), block 256.
// ---------------------------------------------------------------------------
__global__ __launch_bounds__(256) void transpose_cast(
    const float* __restrict__ W, short* __restrict__ Wt, int K, int N) {
  __shared__ float tile[32][33];
  const int n0 = blockIdx.x * 32, k0 = blockIdx.y * 32;
  const int r = threadIdx.x >> 3, c4 = (threadIdx.x & 7) * 4;
  float4 v = *(const float4*)(W + (size_t)(k0 + r) * N + n0 + c4);
  tile[r][c4 + 0] = v.x; tile[r][c4 + 1] = v.y;
  tile[r][c4 + 2] = v.z; tile[r][c4 + 3] = v.w;
  __syncthreads();
  s16x4 o;
  o[0] = f2bf(tile[c4 + 0][r]);
  o[1] = f2bf(tile[c4 + 1][r]);
  o[2] = f2bf(tile[c4 + 2][r]);
  o[3] = f2bf(tile[c4 + 3][r]);
  *(s16x4*)(Wt + (size_t)(n0 + r) * K + k0 + c4) = o;
}

// ---------------------------------------------------------------------------
// bf16 MFMA GEMM (unchanged from round 3).
// ---------------------------------------------------------------------------
template <int N, bool SCATTER>
__global__ __launch_bounds__(256) void gemm_bf16(
    const short* __restrict__ A, const short* __restrict__ Wt,
    const float* __restrict__ bias,
    float* __restrict__ out0, float* __restrict__ out1, float* __restrict__ out2) {
  const int tid = threadIdx.x;
  const int w = tid >> 6, l = tid & 63;
  const int lm = l & 15, lk = l >> 4;
  const int n0 = blockIdx.x * 128 + (w & 1) * 64;
  const int m0 = blockIdx.y * 128 + (w >> 1) * 64;
  const int K = 1024;
  f32x4 acc[4][4];
#pragma unroll
  for (int mi = 0; mi < 4; mi++)
#pragma unroll
    for (int ni = 0; ni < 4; ni++) acc[mi][ni] = (f32x4){0.f, 0.f, 0.f, 0.f};

  for (int k0 = 0; k0 < K; k0 += 32) {
    s16x8 af[4], bf[4];
#pragma unroll
    for (int mi = 0; mi < 4; mi++)
      af[mi] = *(const s16x8*)(A + (size_t)(m0 + mi * 16 + lm) * K + k0 + lk * 8);
#pragma unroll
    for (int ni = 0; ni < 4; ni++)
      bf[ni] = *(const s16x8*)(Wt + (size_t)(n0 + ni * 16 + lm) * K + k0 + lk * 8);
#pragma unroll
    for (int mi = 0; mi < 4; mi++)
#pragma unroll
      for (int ni = 0; ni < 4; ni++)
        acc[mi][ni] = MFMA_BF16(af[mi], bf[ni], acc[mi][ni]);
  }
#pragma unroll
  for (int ni = 0; ni < 4; ni++) {
    const int n = n0 + ni * 16 + lm;
    const float bv = bias[n];
#pragma unroll
    for (int mi = 0; mi < 4; mi++) {
#pragma unroll
      for (int r = 0; r < 4; r++) {
        const int m = m0 + mi * 16 + lk * 4 + r;
        float v = acc[mi][ni][r] + bv;
        if (SCATTER) {
          int three = n >> 10;
          int h = (n >> 7) & 7;
          int dh = n & 127;
          int bb = m >> 11, tt = m & 2047;
          float* dst = (three == 0) ? out0 : ((three == 1) ? out1 : out2);
          dst[((size_t)(bb * 8 + h) * 2048 + tt) * 128 + dh] = v;
        } else {
          out0[(size_t)m * N + n] = v;
        }
      }
    }
  }
}

// ---------------------------------------------------------------------------
// Splat weights -> bf16 qa/kw, layout [b][h][t][s].  (unchanged)
// ---------------------------------------------------------------------------
__global__ __launch_bounds__(256) void splat_weights(
    const float* __restrict__ qT, const float* __restrict__ kT,
    const float* __restrict__ ctr, const float* __restrict__ ls,
    const float* __restrict__ la, short* __restrict__ qa16, short* __restrict__ kw16) {
  const int bt = blockIdx.x;
  const int which = blockIdx.y;
  const int b = bt >> 11, tt = bt & 2047;
  const float* src = which ? kT : qT;
  __shared__ __align__(16) float rowbuf[1024];
  {
    int flat = threadIdx.x * 4;
    int hh = flat >> 7, d = flat & 127;
    *(float4*)&rowbuf[flat] = *(const float4*)(src + ((size_t)(b * 8 + hh) * 2048 + tt) * 128 + d);
  }
  __syncthreads();
  const int h = threadIdx.x >> 5, s = threadIdx.x & 31;
  const float* c = ctr + (h * 32 + s) * 128;
  const float* qr = &rowbuf[h * 128];
  float qsq = 0.f, csq = 0.f, dot = 0.f;
#pragma unroll
  for (int u = 0; u < 32; u++) {
    float4 cv = *(const float4*)(c + u * 4);
    float4 qv = *(const float4*)(qr + u * 4);
    qsq += qv.x * qv.x + qv.y * qv.y + qv.z * qv.z + qv.w * qv.w;
    csq += cv.x * cv.x + cv.y * cv.y + cv.z * cv.z + cv.w * cv.w;
    dot += qv.x * cv.x + qv.y * cv.y + qv.z * cv.z + qv.w * cv.w;
  }
  float d2 = fmaxf(qsq + csq - 2.f * dot, 0.f);
  float scale = __expf(ls[h * 32 + s]);
  float inv = 1.0f / (scale + 1e-6f);
  float w = __expf(-0.5f * d2 * inv * inv);
  if (which == 0) w *= __expf(la[h * 32 + s]);
  short* dst = which ? kw16 : qa16;
  dst[((size_t)(b * 8 + h) * 2048 + tt) * 32 + s] = f2bf(w);
}

// ---------------------------------------------------------------------------
// V transpose: vT fp32 [b][h][t][dh] -> vt16 bf16 [b][h][dh][t]  (unchanged)
// ---------------------------------------------------------------------------
__global__ __launch_bounds__(256) void transpose_v(
    const float* __restrict__ vT, short* __restrict__ vt16) {
  __shared__ float tile[32][33];
  const int t0 = blockIdx.x * 32, d0 = blockIdx.y * 32, bh = blockIdx.z;
  const int r = threadIdx.x >> 3, c4 = (threadIdx.x & 7) * 4;
  float4 v = *(const float4*)(vT + ((size_t)(bh * 2048 + t0 + r)) * 128 + d0 + c4);
  tile[r][c4 + 0] = v.x; tile[r][c4 + 1] = v.y;
  tile[r][c4 + 2] = v.z; tile[r][c4 + 3] = v.w;
  __syncthreads();
  s16x4 o;
  o[0] = f2bf(tile[c4 + 0][r]);
  o[1] = f2bf(tile[c4 + 1][r]);
  o[2] = f2bf(tile[c4 + 2][r]);
  o[3] = f2bf(tile[c4 + 3][r]);
  *(s16x4*)(vt16 + ((size_t)(bh * 128 + d0 + r)) * 2048 + t0 + c4) = o;
}

// ---------------------------------------------------------------------------
// Flash attention v2: j-chunk widened to 64 (4 logit MFMAs per iter) to halve
// shfl-reduction + rescale cost per element; acc rescale skipped when the
// running max didn't change anywhere in the wave (steady state after a few
// chunks).  Wave owns 16 i-rows; grid (T/64, H, B).
// ---------------------------------------------------------------------------
__global__ __launch_bounds__(256) void attn_flash(
    const short* __restrict__ qa16, const short* __restrict__ kw16,
    const short* __restrict__ vt16, const float* __restrict__ temp,
    float* __restrict__ mrow, float* __restrict__ lrow,
    short* __restrict__ aout16) {
  __shared__ float pads[4][16][66];   // 66: lk-stride 264 = 8 mod 32 -> 2-way max
  const int tid = threadIdx.x;
  const int w = tid >> 6, l = tid & 63;
  const int lm = l & 15, lk = l >> 4;
  const int it = blockIdx.x, h = blockIdx.y, b = blockIdx.z;
  const int bh = b * 8 + h;
  const int i0 = it * 64 + w * 16;
  const float invT = 1.0f / temp[0];
  const short* kwb = kw16 + (size_t)bh * 2048 * 32;
  const short* vtb = vt16 + (size_t)bh * 128 * 2048;
  s16x8 qfrag = *(const s16x8*)(qa16 + ((size_t)(bh * 2048 + i0 + lm)) * 32 + lk * 8);
  float m_i[4] = {-1e30f, -1e30f, -1e30f, -1e30f};
  float l_i[4] = {0.f, 0.f, 0.f, 0.f};
  f32x4 acc[8];
#pragma unroll
  for (int d = 0; d < 8; d++) acc[d] = (f32x4){0.f, 0.f, 0.f, 0.f};
  float (*pw)[66] = pads[w];

  for (int jc = 0; jc < 2048; jc += 64) {
    s16x8 kb[4];
#pragma unroll
    for (int c = 0; c < 4; c++)
      kb[c] = *(const s16x8*)(kwb + (size_t)(jc + c * 16 + lm) * 32 + lk * 8);
    f32x4 z = (f32x4){0.f, 0.f, 0.f, 0.f};
    f32x4 s[4];
#pragma unroll
    for (int c = 0; c < 4; c++) s[c] = MFMA_BF16(qfrag, kb[c], z);
    float p[4][4], alpha[4];
#pragma unroll
    for (int r = 0; r < 4; r++) {
      float a0 = s[0][r] * invT, a1 = s[1][r] * invT;
      float a2 = s[2][r] * invT, a3 = s[3][r] * invT;
      float cm = fmaxf(fmaxf(a0, a1), fmaxf(a2, a3));
      cm = fmaxf(cm, __shfl_xor(cm, 1));
      cm = fmaxf(cm, __shfl_xor(cm, 2));
      cm = fmaxf(cm, __shfl_xor(cm, 4));
      cm = fmaxf(cm, __shfl_xor(cm, 8));
      float mn = fmaxf(m_i[r], cm);
      alpha[r] = __expf(m_i[r] - mn);
      m_i[r] = mn;
      p[0][r] = __expf(a0 - mn);
      p[1][r] = __expf(a1 - mn);
      p[2][r] = __expf(a2 - mn);
      p[3][r] = __expf(a3 - mn);
      float rs = p[0][r] + p[1][r] + p[2][r] + p[3][r];
      rs += __shfl_xor(rs, 1);
      rs += __shfl_xor(rs, 2);
      rs += __shfl_xor(rs, 4);
      rs += __shfl_xor(rs, 8);
      l_i[r] = l_i[r] * alpha[r] + rs;
    }
    bool ch = (alpha[0] != 1.f) | (alpha[1] != 1.f) | (alpha[2] != 1.f) | (alpha[3] != 1.f);
    if (__any(ch)) {
#pragma unroll
      for (int d = 0; d < 8; d++)
#pragma unroll
        for (int r = 0; r < 4; r++) acc[d][r] *= alpha[r];
    }
    // P: C-layout -> LDS -> A-layout (two 16x16x32 fragments covering j 0..63)
#pragma unroll
    for (int c = 0; c < 4; c++)
#pragma unroll
      for (int r = 0; r < 4; r++) pw[lk * 4 + r][c * 16 + lm] = p[c][r];
    s16x8 pf0, pf1;
#pragma unroll
    for (int j = 0; j < 8; j++) {
      pf0[j] = f2bf(pw[lm][lk * 8 + j]);
      pf1[j] = f2bf(pw[lm][32 + lk * 8 + j]);
    }
#pragma unroll
    for (int d = 0; d < 8; d++) {
      const short* vrow = vtb + (size_t)(d * 16 + lm) * 2048 + jc;
      s16x8 vb0 = *(const s16x8*)(vrow + lk * 8);
      s16x8 vb1 = *(const s16x8*)(vrow + 32 + lk * 8);
      acc[d] = MFMA_BF16(pf0, vb0, acc[d]);
      acc[d] = MFMA_BF16(pf1, vb1, acc[d]);
    }
  }
  float invl[4];
#pragma unroll
  for (int r = 0; r < 4; r++) invl[r] = 1.0f / l_i[r];
#pragma unroll
  for (int r = 0; r < 4; r++) {
    int row = i0 + lk * 4 + r;
    short* ob = aout16 + (size_t)(b * 2048 + row) * 1024 + h * 128 + lm;
#pragma unroll
    for (int d = 0; d < 8; d++) ob[d * 16] = f2bf(acc[d][r] * invl[r]);
  }
  if (lm == 0) {
#pragma unroll
    for (int r = 0; r < 4; r++) {
      mrow[bh * 2048 + i0 + lk * 4 + r] = m_i[r];
      lrow[bh * 2048 + i0 + lk * 4 + r] = l_i[r];
    }
  }
}

// ---------------------------------------------------------------------------
// Attention write v3: MFMA recompute -> LDS tile -> fully coalesced float4
// stores (each wave-instruction covers 1 KB contiguous).  Fixes the 2.2x
// write amplification of v2 (596 MB -> ~278 MB).
// Block = (b, 32 i, 32 j), 4 waves; wave w computes h = 2w, 2w+1.
// ---------------------------------------------------------------------------
__global__ __launch_bounds__(256) void attn_write(
    const short* __restrict__ qa16, const short* __restrict__ kw16,
    const float* __restrict__ mrow, const float* __restrict__ lrow,
    const float* __restrict__ temp, float* __restrict__ attn) {
  __shared__ float pl[8][32][33];   // [h][i][j], j padded: 33 KB
  const int tid = threadIdx.x;
  const int w = tid >> 6, l = tid & 63;
  const int lm = l & 15, lk = l >> 4;
  const int i0 = blockIdx.x * 32, j0 = blockIdx.y * 32, b = blockIdx.z;
  const float invT = 1.0f / temp[0];
#pragma unroll
  for (int hh = 0; hh < 2; hh++) {
    const int h = w * 2 + hh;
    const int bh = b * 8 + h;
    s16x8 qf[2], kf[2];
#pragma unroll
    for (int ih = 0; ih < 2; ih++)
      qf[ih] = *(const s16x8*)(qa16 + ((size_t)(bh * 2048 + i0 + ih * 16 + lm)) * 32 + lk * 8);
#pragma unroll
    for (int jh = 0; jh < 2; jh++)
      kf[jh] = *(const s16x8*)(kw16 + ((size_t)(bh * 2048 + j0 + jh * 16 + lm)) * 32 + lk * 8);
    float mv[2][4], il[2][4];
#pragma unroll
    for (int ih = 0; ih < 2; ih++)
#pragma unroll
      for (int r = 0; r < 4; r++) {
        int i = i0 + ih * 16 + lk * 4 + r;
        mv[ih][r] = mrow[bh * 2048 + i];
        il[ih][r] = 1.0f / lrow[bh * 2048 + i];
      }
    f32x4 z = (f32x4){0.f, 0.f, 0.f, 0.f};
#pragma unroll
    for (int ih = 0; ih < 2; ih++) {
#pragma unroll
      for (int jh = 0; jh < 2; jh++) {
        f32x4 s = MFMA_BF16(qf[ih], kf[jh], z);
#pragma unroll
        for (int r = 0; r < 4; r++) {
          float p = __expf(s[r] * invT - mv[ih][r]) * il[ih][r];
          pl[h][ih * 16 + lk * 4 + r][jh * 16 + lm] = p;
        }
      }
    }
  }
  __syncthreads();
  // Readout: flat mapping; per wave-instruction, 64 lanes cover one i-row's
  // 32j x 8h = 1 KB contiguous region as float4 (h fastest).
#pragma unroll
  for (int c = 0; c < 8; c++) {
    int u = c * 256 + tid;
    int i = u >> 6, rem = u & 63;
    int j = rem >> 1, h4 = (rem & 1) * 4;
    float4 v = make_float4(pl[h4][i][j], pl[h4 + 1][i][j],
                           pl[h4 + 2][i][j], pl[h4 + 3][i][j]);
    *(float4*)(attn + (((size_t)(b * 2048 + i0 + i)) * 2048 + j0 + j) * 8 + h4) = v;
  }
}

// ---------------------------------------------------------------------------
extern "C" void kernel_launch(void* const* d_in, const int* in_sizes, int n_in,
                              void* d_out, int out_size, void* d_ws, size_t ws_size,
                              hipStream_t stream) {
  const float* x    = (const float*)d_in[0];
  const float* Wqkv = (const float*)d_in[1];
  const float* bqkv = (const float*)d_in[2];
  const float* Wout = (const float*)d_in[3];
  const float* bout = (const float*)d_in[4];
  const float* ctr  = (const float*)d_in[5];
  const float* ls   = (const float*)d_in[6];
  const float* la   = (const float*)d_in[7];
  const float* temp = (const float*)d_in[8];

  float* out = (float*)d_out;                 // (B,T,D)
  float* attn = out + 4194304;                // (B,T,T,H)

  float* ws = (float*)d_ws;
  float* qT    = ws;                          // 4,194,304 fp32
  float* kT    = qT + 4194304;
  float* vT    = kT + 4194304;
  short* x16   = (short*)(vT + 4194304);      // 4,194,304 shorts
  short* Wqt16 = x16 + 4194304;               // 3,145,728 shorts
  short* qa16  = Wqt16 + 3145728;             // 1,048,576 shorts
  short* kw16  = qa16 + 1048576;
  float* mrow  = (float*)(kw16 + 1048576);    // 32,768 fp32
  float* lrow  = mrow + 32768;
  short* vt16  = (short*)ws;                  // aliases qT[0:8MB]   (after splat)
  short* Wot16 = (short*)ws + 4194304;        // aliases qT[8:10MB]  (after splat)
  short* aout16 = (short*)vT;                 // aliases vT          (after transpose_v)

  cast_bf16<<<4096, 256, 0, stream>>>(x, x16, 1048576);
  transpose_cast<<<dim3(96, 32), 256, 0, stream>>>(Wqkv, Wqt16, 1024, 3072);
  gemm_bf16<3072, true><<<dim3(24, 32), 256, 0, stream>>>(x16, Wqt16, bqkv, qT, kT, vT);
  splat_weights<<<dim3(4096, 2), 256, 0, stream>>>(qT, kT, ctr, ls, la, qa16, kw16);
  transpose_v<<<dim3(64, 4, 16), 256, 0, stream>>>(vT, vt16);
  transpose_cast<<<dim3(32, 32), 256, 0, stream>>>(Wout, Wot16, 1024, 1024);
  attn_flash<<<dim3(32, 8, 2), 256, 0, stream>>>(qa16, kw16, vt16, temp, mrow, lrow, aout16);
  attn_write<<<dim3(64, 64, 2), 256, 0, stream>>>(qa16, kw16, mrow, lrow, temp, attn);
  gemm_bf16<1024, false><<<dim3(8, 32), 256, 0, stream>>>(aout16, Wot16, bout, out, nullptr, nullptr);
}

// Round 5
// 657.480 us; speedup vs baseline: 2.8466x; 1.2404x over previous
//
#include <hip/hip_runtime.h>
#include <math.h>

// Shapes: B=2, T=2048, D=1024, H=8, S=32, Dh=128, 3D=3072, B*T=4096

typedef __attribute__((ext_vector_type(8))) short s16x8;
typedef __attribute__((ext_vector_type(4))) short s16x4;
typedef __attribute__((ext_vector_type(4))) float f32x4;

__device__ inline short f2bf(float f) {
  union { float f; unsigned u; } v; v.f = f;
  unsigned r = v.u + 0x7FFFu + ((v.u >> 16) & 1u);
  return (short)(r >> 16);
}
__device__ inline float bf2f(short s) {
  union { unsigned u; float f; } v;
  v.u = ((unsigned)(unsigned short)s) << 16;
  return v.f;
}
#define MFMA_BF16(a, b, c) __builtin_amdgcn_mfma_f32_16x16x32_bf16((a), (b), (c), 0, 0, 0)

// ---------------------------------------------------------------------------
// Elementwise fp32 -> bf16 cast (n4 = count/4).
// ---------------------------------------------------------------------------
__global__ __launch_bounds__(256) void cast_bf16(
    const float* __restrict__ in, short* __restrict__ out, int n4) {
  int i = blockIdx.x * 256 + threadIdx.x;
  if (i < n4) {
    float4 v = ((const float4*)in)[i];
    s16x4 o;
    o[0] = f2bf(v.x); o[1] = f2bf(v.y); o[2] = f2bf(v.z); o[3] = f2bf(v.w);
    ((s16x4*)out)[i] = o;
  }
}

// ---------------------------------------------------------------------------
// W[K][N] fp32 -> Wt[N][K] bf16.  grid (N/32, K/32), block 256.
// ---------------------------------------------------------------------------
__global__ __launch_bounds__(256) void transpose_cast(
    const float* __restrict__ W, short* __restrict__ Wt, int K, int N) {
  __shared__ float tile[32][33];
  const int n0 = blockIdx.x * 32, k0 = blockIdx.y * 32;
  const int r = threadIdx.x >> 3, c4 = (threadIdx.x & 7) * 4;
  float4 v = *(const float4*)(W + (size_t)(k0 + r) * N + n0 + c4);
  tile[r][c4 + 0] = v.x; tile[r][c4 + 1] = v.y;
  tile[r][c4 + 2] = v.z; tile[r][c4 + 3] = v.w;
  __syncthreads();
  s16x4 o;
  o[0] = f2bf(tile[c4 + 0][r]);
  o[1] = f2bf(tile[c4 + 1][r]);
  o[2] = f2bf(tile[c4 + 2][r]);
  o[3] = f2bf(tile[c4 + 3][r]);
  *(s16x4*)(Wt + (size_t)(n0 + r) * K + k0 + c4) = o;
}

// ---------------------------------------------------------------------------
// bf16 MFMA GEMM (unchanged).
// ---------------------------------------------------------------------------
template <int N, bool SCATTER>
__global__ __launch_bounds__(256) void gemm_bf16(
    const short* __restrict__ A, const short* __restrict__ Wt,
    const float* __restrict__ bias,
    float* __restrict__ out0, float* __restrict__ out1, float* __restrict__ out2) {
  const int tid = threadIdx.x;
  const int w = tid >> 6, l = tid & 63;
  const int lm = l & 15, lk = l >> 4;
  const int n0 = blockIdx.x * 128 + (w & 1) * 64;
  const int m0 = blockIdx.y * 128 + (w >> 1) * 64;
  const int K = 1024;
  f32x4 acc[4][4];
#pragma unroll
  for (int mi = 0; mi < 4; mi++)
#pragma unroll
    for (int ni = 0; ni < 4; ni++) acc[mi][ni] = (f32x4){0.f, 0.f, 0.f, 0.f};

  for (int k0 = 0; k0 < K; k0 += 32) {
    s16x8 af[4], bf[4];
#pragma unroll
    for (int mi = 0; mi < 4; mi++)
      af[mi] = *(const s16x8*)(A + (size_t)(m0 + mi * 16 + lm) * K + k0 + lk * 8);
#pragma unroll
    for (int ni = 0; ni < 4; ni++)
      bf[ni] = *(const s16x8*)(Wt + (size_t)(n0 + ni * 16 + lm) * K + k0 + lk * 8);
#pragma unroll
    for (int mi = 0; mi < 4; mi++)
#pragma unroll
      for (int ni = 0; ni < 4; ni++)
        acc[mi][ni] = MFMA_BF16(af[mi], bf[ni], acc[mi][ni]);
  }
#pragma unroll
  for (int ni = 0; ni < 4; ni++) {
    const int n = n0 + ni * 16 + lm;
    const float bv = bias[n];
#pragma unroll
    for (int mi = 0; mi < 4; mi++) {
#pragma unroll
      for (int r = 0; r < 4; r++) {
        const int m = m0 + mi * 16 + lk * 4 + r;
        float v = acc[mi][ni][r] + bv;
        if (SCATTER) {
          int three = n >> 10;
          int h = (n >> 7) & 7;
          int dh = n & 127;
          int bb = m >> 11, tt = m & 2047;
          float* dst = (three == 0) ? out0 : ((three == 1) ? out1 : out2);
          dst[((size_t)(bb * 8 + h) * 2048 + tt) * 128 + dh] = v;
        } else {
          out0[(size_t)m * N + n] = v;
        }
      }
    }
  }
}

// ---------------------------------------------------------------------------
// Splat prep (1 block): centers -> bf16 [h][s][dh]; csq, inv2=-0.5/(e^ls+eps)^2,
// amp = e^la per (h,s).
// ---------------------------------------------------------------------------
__global__ __launch_bounds__(256) void splat_prep(
    const float* __restrict__ ctr, const float* __restrict__ ls,
    const float* __restrict__ la, short* __restrict__ c16,
    float* __restrict__ csq, float* __restrict__ inv2, float* __restrict__ amp) {
  const int t = threadIdx.x;   // (h*32+s)
  float sumsq = 0.f;
#pragma unroll
  for (int d = 0; d < 128; d += 4) {
    float4 v = *(const float4*)(ctr + (size_t)t * 128 + d);
    sumsq += v.x * v.x + v.y * v.y + v.z * v.z + v.w * v.w;
    s16x4 o;
    o[0] = f2bf(v.x); o[1] = f2bf(v.y); o[2] = f2bf(v.z); o[3] = f2bf(v.w);
    *(s16x4*)(c16 + (size_t)t * 128 + d) = o;
  }
  csq[t] = sumsq;
  float sc = __expf(ls[t]);
  float iv = 1.0f / (sc + 1e-6f);
  inv2[t] = -0.5f * iv * iv;
  amp[t] = __expf(la[t]);
}

// ---------------------------------------------------------------------------
// Splat weights v2: per-head MFMA GEMM  dots[t][s] = q[t]·c[s]  (K=128, N=32).
// Wave owns 16 t-rows; q loaded fp32 (coalesced 128B segments), converted to
// bf16 A-frags inline; qsq accumulated fp32 from same loads, shfl-reduced.
// w = exp(inv2*max(qsq+csq-2dot,0))*amp -> bf16 [b][h][t][s].  No LDS.
// Grid (T/64, B*H, 2).
// ---------------------------------------------------------------------------
__global__ __launch_bounds__(256) void splat_mfma(
    const float* __restrict__ qT, const float* __restrict__ kT,
    const short* __restrict__ c16, const float* __restrict__ csq,
    const float* __restrict__ inv2, const float* __restrict__ amp,
    short* __restrict__ qa16, short* __restrict__ kw16) {
  const int tid = threadIdx.x;
  const int w = tid >> 6, l = tid & 63;
  const int lm = l & 15, lk = l >> 4;
  const int it = blockIdx.x, bh = blockIdx.y, which = blockIdx.z;
  const int h = bh & 7;
  const int i0 = it * 64 + w * 16;
  const float* src = which ? kT : qT;

  s16x8 af[4];
  float sq = 0.f;
#pragma unroll
  for (int kk = 0; kk < 4; kk++) {
    const float* p = src + ((size_t)bh * 2048 + i0 + lm) * 128 + kk * 32 + lk * 8;
    float4 v0 = *(const float4*)p;
    float4 v1 = *(const float4*)(p + 4);
    sq += v0.x * v0.x + v0.y * v0.y + v0.z * v0.z + v0.w * v0.w +
          v1.x * v1.x + v1.y * v1.y + v1.z * v1.z + v1.w * v1.w;
    af[kk][0] = f2bf(v0.x); af[kk][1] = f2bf(v0.y);
    af[kk][2] = f2bf(v0.z); af[kk][3] = f2bf(v0.w);
    af[kk][4] = f2bf(v1.x); af[kk][5] = f2bf(v1.y);
    af[kk][6] = f2bf(v1.z); af[kk][7] = f2bf(v1.w);
  }
  sq += __shfl_xor(sq, 16);
  sq += __shfl_xor(sq, 32);   // lanes 0..15 now hold qsq[row i0+lm]

  f32x4 acc[2];
  acc[0] = (f32x4){0.f, 0.f, 0.f, 0.f};
  acc[1] = (f32x4){0.f, 0.f, 0.f, 0.f};
#pragma unroll
  for (int kk = 0; kk < 4; kk++) {
    s16x8 b0 = *(const s16x8*)(c16 + (size_t)(h * 32 + lm) * 128 + kk * 32 + lk * 8);
    s16x8 b1 = *(const s16x8*)(c16 + (size_t)(h * 32 + 16 + lm) * 128 + kk * 32 + lk * 8);
    acc[0] = MFMA_BF16(af[kk], b0, acc[0]);
    acc[1] = MFMA_BF16(af[kk], b1, acc[1]);
  }
  short* dst = which ? kw16 : qa16;
#pragma unroll
  for (int ni = 0; ni < 2; ni++) {
    const int n = ni * 16 + lm;
    const float cs = csq[h * 32 + n];
    const float iv2 = inv2[h * 32 + n];
    const float am = which ? 1.0f : amp[h * 32 + n];
#pragma unroll
    for (int r = 0; r < 4; r++) {
      float qs = __shfl(sq, lk * 4 + r);
      float d2 = fmaxf(qs + cs - 2.0f * acc[ni][r], 0.0f);
      float wv = __expf(iv2 * d2) * am;
      int m = i0 + lk * 4 + r;
      dst[((size_t)bh * 2048 + m) * 32 + n] = f2bf(wv);
    }
  }
}

// ---------------------------------------------------------------------------
// V transpose: vT fp32 [b][h][t][dh] -> vt16 bf16 [b][h][dh][t]  (unchanged)
// ---------------------------------------------------------------------------
__global__ __launch_bounds__(256) void transpose_v(
    const float* __restrict__ vT, short* __restrict__ vt16) {
  __shared__ float tile[32][33];
  const int t0 = blockIdx.x * 32, d0 = blockIdx.y * 32, bh = blockIdx.z;
  const int r = threadIdx.x >> 3, c4 = (threadIdx.x & 7) * 4;
  float4 v = *(const float4*)(vT + ((size_t)(bh * 2048 + t0 + r)) * 128 + d0 + c4);
  tile[r][c4 + 0] = v.x; tile[r][c4 + 1] = v.y;
  tile[r][c4 + 2] = v.z; tile[r][c4 + 3] = v.w;
  __syncthreads();
  s16x4 o;
  o[0] = f2bf(tile[c4 + 0][r]);
  o[1] = f2bf(tile[c4 + 1][r]);
  o[2] = f2bf(tile[c4 + 2][r]);
  o[3] = f2bf(tile[c4 + 3][r]);
  *(s16x4*)(vt16 + ((size_t)(bh * 128 + d0 + r)) * 2048 + t0 + c4) = o;
}

// ---------------------------------------------------------------------------
// Flash attention v2 (unchanged from round 4).
// ---------------------------------------------------------------------------
__global__ __launch_bounds__(256) void attn_flash(
    const short* __restrict__ qa16, const short* __restrict__ kw16,
    const short* __restrict__ vt16, const float* __restrict__ temp,
    float* __restrict__ mrow, float* __restrict__ lrow,
    short* __restrict__ aout16) {
  __shared__ float pads[4][16][66];
  const int tid = threadIdx.x;
  const int w = tid >> 6, l = tid & 63;
  const int lm = l & 15, lk = l >> 4;
  const int it = blockIdx.x, h = blockIdx.y, b = blockIdx.z;
  const int bh = b * 8 + h;
  const int i0 = it * 64 + w * 16;
  const float invT = 1.0f / temp[0];
  const short* kwb = kw16 + (size_t)bh * 2048 * 32;
  const short* vtb = vt16 + (size_t)bh * 128 * 2048;
  s16x8 qfrag = *(const s16x8*)(qa16 + ((size_t)(bh * 2048 + i0 + lm)) * 32 + lk * 8);
  float m_i[4] = {-1e30f, -1e30f, -1e30f, -1e30f};
  float l_i[4] = {0.f, 0.f, 0.f, 0.f};
  f32x4 acc[8];
#pragma unroll
  for (int d = 0; d < 8; d++) acc[d] = (f32x4){0.f, 0.f, 0.f, 0.f};
  float (*pw)[66] = pads[w];

  for (int jc = 0; jc < 2048; jc += 64) {
    s16x8 kb[4];
#pragma unroll
    for (int c = 0; c < 4; c++)
      kb[c] = *(const s16x8*)(kwb + (size_t)(jc + c * 16 + lm) * 32 + lk * 8);
    f32x4 z = (f32x4){0.f, 0.f, 0.f, 0.f};
    f32x4 s[4];
#pragma unroll
    for (int c = 0; c < 4; c++) s[c] = MFMA_BF16(qfrag, kb[c], z);
    float p[4][4], alpha[4];
#pragma unroll
    for (int r = 0; r < 4; r++) {
      float a0 = s[0][r] * invT, a1 = s[1][r] * invT;
      float a2 = s[2][r] * invT, a3 = s[3][r] * invT;
      float cm = fmaxf(fmaxf(a0, a1), fmaxf(a2, a3));
      cm = fmaxf(cm, __shfl_xor(cm, 1));
      cm = fmaxf(cm, __shfl_xor(cm, 2));
      cm = fmaxf(cm, __shfl_xor(cm, 4));
      cm = fmaxf(cm, __shfl_xor(cm, 8));
      float mn = fmaxf(m_i[r], cm);
      alpha[r] = __expf(m_i[r] - mn);
      m_i[r] = mn;
      p[0][r] = __expf(a0 - mn);
      p[1][r] = __expf(a1 - mn);
      p[2][r] = __expf(a2 - mn);
      p[3][r] = __expf(a3 - mn);
      float rs = p[0][r] + p[1][r] + p[2][r] + p[3][r];
      rs += __shfl_xor(rs, 1);
      rs += __shfl_xor(rs, 2);
      rs += __shfl_xor(rs, 4);
      rs += __shfl_xor(rs, 8);
      l_i[r] = l_i[r] * alpha[r] + rs;
    }
    bool ch = (alpha[0] != 1.f) | (alpha[1] != 1.f) | (alpha[2] != 1.f) | (alpha[3] != 1.f);
    if (__any(ch)) {
#pragma unroll
      for (int d = 0; d < 8; d++)
#pragma unroll
        for (int r = 0; r < 4; r++) acc[d][r] *= alpha[r];
    }
#pragma unroll
    for (int c = 0; c < 4; c++)
#pragma unroll
      for (int r = 0; r < 4; r++) pw[lk * 4 + r][c * 16 + lm] = p[c][r];
    s16x8 pf0, pf1;
#pragma unroll
    for (int j = 0; j < 8; j++) {
      pf0[j] = f2bf(pw[lm][lk * 8 + j]);
      pf1[j] = f2bf(pw[lm][32 + lk * 8 + j]);
    }
#pragma unroll
    for (int d = 0; d < 8; d++) {
      const short* vrow = vtb + (size_t)(d * 16 + lm) * 2048 + jc;
      s16x8 vb0 = *(const s16x8*)(vrow + lk * 8);
      s16x8 vb1 = *(const s16x8*)(vrow + 32 + lk * 8);
      acc[d] = MFMA_BF16(pf0, vb0, acc[d]);
      acc[d] = MFMA_BF16(pf1, vb1, acc[d]);
    }
  }
  float invl[4];
#pragma unroll
  for (int r = 0; r < 4; r++) invl[r] = 1.0f / l_i[r];
#pragma unroll
  for (int r = 0; r < 4; r++) {
    int row = i0 + lk * 4 + r;
    short* ob = aout16 + (size_t)(b * 2048 + row) * 1024 + h * 128 + lm;
#pragma unroll
    for (int d = 0; d < 8; d++) ob[d * 16] = f2bf(acc[d][r] * invl[r]);
  }
  if (lm == 0) {
#pragma unroll
    for (int r = 0; r < 4; r++) {
      mrow[bh * 2048 + i0 + lk * 4 + r] = m_i[r];
      lrow[bh * 2048 + i0 + lk * 4 + r] = l_i[r];
    }
  }
}

// ---------------------------------------------------------------------------
// Attention write v3 (unchanged from round 4).
// ---------------------------------------------------------------------------
__global__ __launch_bounds__(256) void attn_write(
    const short* __restrict__ qa16, const short* __restrict__ kw16,
    const float* __restrict__ mrow, const float* __restrict__ lrow,
    const float* __restrict__ temp, float* __restrict__ attn) {
  __shared__ float pl[8][32][33];
  const int tid = threadIdx.x;
  const int w = tid >> 6, l = tid & 63;
  const int lm = l & 15, lk = l >> 4;
  const int i0 = blockIdx.x * 32, j0 = blockIdx.y * 32, b = blockIdx.z;
  const float invT = 1.0f / temp[0];
#pragma unroll
  for (int hh = 0; hh < 2; hh++) {
    const int h = w * 2 + hh;
    const int bh = b * 8 + h;
    s16x8 qf[2], kf[2];
#pragma unroll
    for (int ih = 0; ih < 2; ih++)
      qf[ih] = *(const s16x8*)(qa16 + ((size_t)(bh * 2048 + i0 + ih * 16 + lm)) * 32 + lk * 8);
#pragma unroll
    for (int jh = 0; jh < 2; jh++)
      kf[jh] = *(const s16x8*)(kw16 + ((size_t)(bh * 2048 + j0 + jh * 16 + lm)) * 32 + lk * 8);
    float mv[2][4], il[2][4];
#pragma unroll
    for (int ih = 0; ih < 2; ih++)
#pragma unroll
      for (int r = 0; r < 4; r++) {
        int i = i0 + ih * 16 + lk * 4 + r;
        mv[ih][r] = mrow[bh * 2048 + i];
        il[ih][r] = 1.0f / lrow[bh * 2048 + i];
      }
    f32x4 z = (f32x4){0.f, 0.f, 0.f, 0.f};
#pragma unroll
    for (int ih = 0; ih < 2; ih++) {
#pragma unroll
      for (int jh = 0; jh < 2; jh++) {
        f32x4 s = MFMA_BF16(qf[ih], kf[jh], z);
#pragma unroll
        for (int r = 0; r < 4; r++) {
          float p = __expf(s[r] * invT - mv[ih][r]) * il[ih][r];
          pl[h][ih * 16 + lk * 4 + r][jh * 16 + lm] = p;
        }
      }
    }
  }
  __syncthreads();
#pragma unroll
  for (int c = 0; c < 8; c++) {
    int u = c * 256 + tid;
    int i = u >> 6, rem = u & 63;
    int j = rem >> 1, h4 = (rem & 1) * 4;
    float4 v = make_float4(pl[h4][i][j], pl[h4 + 1][i][j],
                           pl[h4 + 2][i][j], pl[h4 + 3][i][j]);
    *(float4*)(attn + (((size_t)(b * 2048 + i0 + i)) * 2048 + j0 + j) * 8 + h4) = v;
  }
}

// ---------------------------------------------------------------------------
extern "C" void kernel_launch(void* const* d_in, const int* in_sizes, int n_in,
                              void* d_out, int out_size, void* d_ws, size_t ws_size,
                              hipStream_t stream) {
  const float* x    = (const float*)d_in[0];
  const float* Wqkv = (const float*)d_in[1];
  const float* bqkv = (const float*)d_in[2];
  const float* Wout = (const float*)d_in[3];
  const float* bout = (const float*)d_in[4];
  const float* ctr  = (const float*)d_in[5];
  const float* ls   = (const float*)d_in[6];
  const float* la   = (const float*)d_in[7];
  const float* temp = (const float*)d_in[8];

  float* out = (float*)d_out;                 // (B,T,D)
  float* attn = out + 4194304;                // (B,T,T,H)

  float* ws = (float*)d_ws;
  float* qT    = ws;                          // 4,194,304 fp32
  float* kT    = qT + 4194304;
  float* vT    = kT + 4194304;
  short* x16   = (short*)(vT + 4194304);      // 4,194,304 shorts
  short* Wqt16 = x16 + 4194304;               // 3,145,728 shorts
  short* qa16  = Wqt16 + 3145728;             // 1,048,576 shorts
  short* kw16  = qa16 + 1048576;
  float* mrow  = (float*)(kw16 + 1048576);    // 32,768 fp32
  float* lrow  = mrow + 32768;
  float* csq   = lrow + 32768;                // 256
  float* inv2  = csq + 256;                   // 256
  float* amp   = inv2 + 256;                  // 256
  short* c16   = (short*)(amp + 256);         // 32,768 shorts
  short* vt16  = (short*)ws;                  // aliases qT[0:8MB]   (after splat)
  short* Wot16 = (short*)ws + 4194304;        // aliases qT[8:10MB]  (after splat)
  short* aout16 = (short*)vT;                 // aliases vT          (after transpose_v)

  splat_prep<<<1, 256, 0, stream>>>(ctr, ls, la, c16, csq, inv2, amp);
  cast_bf16<<<4096, 256, 0, stream>>>(x, x16, 1048576);
  transpose_cast<<<dim3(96, 32), 256, 0, stream>>>(Wqkv, Wqt16, 1024, 3072);
  gemm_bf16<3072, true><<<dim3(24, 32), 256, 0, stream>>>(x16, Wqt16, bqkv, qT, kT, vT);
  splat_mfma<<<dim3(32, 16, 2), 256, 0, stream>>>(qT, kT, c16, csq, inv2, amp, qa16, kw16);
  transpose_v<<<dim3(64, 4, 16), 256, 0, stream>>>(vT, vt16);
  transpose_cast<<<dim3(32, 32), 256, 0, stream>>>(Wout, Wot16, 1024, 1024);
  attn_flash<<<dim3(32, 8, 2), 256, 0, stream>>>(qa16, kw16, vt16, temp, mrow, lrow, aout16);
  attn_write<<<dim3(64, 64, 2), 256, 0, stream>>>(qa16, kw16, mrow, lrow, temp, attn);
  gemm_bf16<1024, false><<<dim3(8, 32), 256, 0, stream>>>(aout16, Wot16, bout, out, nullptr, nullptr);
}